// Round 1
// baseline (5419.431 us; speedup 1.0000x reference)
//
#include <hip/hip_runtime.h>
#include <hip/hip_bf16.h>
#include <cstdint>

// Layouts:
//   Y1 (bf16, N x 640):  [ q(128: h*64+d) | t(256: h*128+f) | k(128) | m(128) ]
//   Xagg (f32, N x 384): [ magg(128: h*64+d) | s(256: h*128+f) ]  (atomic accum, unnormalized)
//   W1 (f32, 128 x 640): projection weights (q | A(t) | k | m)
//   W2 (f32, 640 x 64):  [ w_h_entity(128) | P_h = w_m@w_h_e (256) | w_h_dialogue(256) ]

__device__ __forceinline__ unsigned short f2bf(float x) {
    unsigned int u = __float_as_uint(x);
    u += 0x7FFFu + ((u >> 16) & 1u);   // round-to-nearest-even
    return (unsigned short)(u >> 16);
}
__device__ __forceinline__ float bflo(unsigned int u) { return __uint_as_float(u << 16); }
__device__ __forceinline__ float bfhi(unsigned int u) { return __uint_as_float(u & 0xFFFF0000u); }

__global__ void zero_f4(float4* __restrict__ p, long n4) {
    long i = (long)blockIdx.x * blockDim.x + threadIdx.x;
    long stride = (long)gridDim.x * blockDim.x;
    float4 z = make_float4(0.f, 0.f, 0.f, 0.f);
    for (; i < n4; i += stride) p[i] = z;
}

__global__ void build_w1(const float* __restrict__ wm, const float* __restrict__ wq,
                         const float* __restrict__ wk, float* __restrict__ W1) {
    int idx = blockIdx.x * blockDim.x + threadIdx.x;
    if (idx >= 128 * 640) return;
    int f = idx / 640, c = idx % 640;
    float v;
    if (c < 128) {                       // q
        int h = c >> 6, dd = c & 63;
        v = wq[h * 8192 + f * 64 + dd];
    } else if (c < 384) {                // t:  A[h,f,f2] = sum_d wq[h,f,d]*wm[h,f2,d]
        int cc = c - 128, h = cc >> 7, f2 = cc & 127;
        float s = 0.f;
        for (int dd = 0; dd < 64; ++dd)
            s += wq[h * 8192 + f * 64 + dd] * wm[h * 8192 + f2 * 64 + dd];
        v = s;
    } else if (c < 512) {                // k
        int cc = c - 384, h = cc >> 6, dd = cc & 63;
        v = wk[h * 8192 + f * 64 + dd];
    } else {                             // m
        int cc = c - 512, h = cc >> 6, dd = cc & 63;
        v = wm[h * 8192 + f * 64 + dd];
    }
    W1[idx] = v;
}

__global__ void build_w2(const float* __restrict__ wm, const float* __restrict__ whe,
                         const float* __restrict__ whd, float* __restrict__ W2) {
    int idx = blockIdx.x * blockDim.x + threadIdx.x;
    if (idx >= 640 * 64) return;
    int rr = idx / 64, j = idx % 64;
    float v;
    if (rr < 128) {                      // magg path: w_h_entity rows (h*64+d)
        v = whe[rr * 64 + j];
    } else if (rr < 384) {               // s path: P_h[f2,j] = sum_d wm[h,f2,d]*whe[h*64+d, j]
        int cc = rr - 128, h = cc >> 7, f2 = cc & 127;
        float s = 0.f;
        for (int dd = 0; dd < 64; ++dd)
            s += wm[h * 8192 + f2 * 64 + dd] * whe[(h * 64 + dd) * 64 + j];
        v = s;
    } else {                             // dialogue path
        v = whd[(rr - 384) * 64 + j];
    }
    W2[idx] = v;
}

// Y1 = entity_features (M x 128) @ W1 (128 x 640), stored bf16.
__global__ __launch_bounds__(256) void gemm_proj(
        const float* __restrict__ F, const float* __restrict__ W1,
        unsigned short* __restrict__ Y1, int M) {
    __shared__ float As[128 * 68];   // transposed [k][m], pad 64->68
    __shared__ float Bs[128 * 64];   // [k][n]
    int m0 = blockIdx.x * 64;
    int bn = blockIdx.y;
    int tid = threadIdx.x;
    #pragma unroll
    for (int i = 0; i < 8; ++i) {
        int s = tid + i * 256;          // 2048 float4 slots: 64 rows x 32 cv
        int row = s >> 5, cv = s & 31;
        int gr = m0 + row;
        float4 v = make_float4(0.f, 0.f, 0.f, 0.f);
        if (gr < M) v = *(const float4*)(F + (size_t)gr * 128 + cv * 4);
        int k0 = cv * 4;
        As[(k0 + 0) * 68 + row] = v.x;
        As[(k0 + 1) * 68 + row] = v.y;
        As[(k0 + 2) * 68 + row] = v.z;
        As[(k0 + 3) * 68 + row] = v.w;
    }
    #pragma unroll
    for (int i = 0; i < 8; ++i) {
        int s = tid + i * 256;          // 2048 float4 slots: 128 k x 16 cv
        int k = s >> 4, cv = s & 15;
        float4 v = *(const float4*)(W1 + (size_t)k * 640 + bn * 64 + cv * 4);
        *(float4*)(Bs + k * 64 + cv * 4) = v;
    }
    __syncthreads();
    int tx = tid & 15, ty = tid >> 4;
    float acc[4][4] = {};
    #pragma unroll 8
    for (int k = 0; k < 128; ++k) {
        float a[4];
        a[0] = As[k * 68 + ty * 4 + 0];
        a[1] = As[k * 68 + ty * 4 + 1];
        a[2] = As[k * 68 + ty * 4 + 2];
        a[3] = As[k * 68 + ty * 4 + 3];
        float4 b = *(const float4*)(Bs + k * 64 + tx * 4);
        #pragma unroll
        for (int i = 0; i < 4; ++i) {
            acc[i][0] += a[i] * b.x;
            acc[i][1] += a[i] * b.y;
            acc[i][2] += a[i] * b.z;
            acc[i][3] += a[i] * b.w;
        }
    }
    #pragma unroll
    for (int i = 0; i < 4; ++i) {
        int gr = m0 + ty * 4 + i;
        if (gr < M) {
            ushort4 st;
            st.x = f2bf(acc[i][0]);
            st.y = f2bf(acc[i][1]);
            st.z = f2bf(acc[i][2]);
            st.w = f2bf(acc[i][3]);
            *(ushort4*)(Y1 + (size_t)gr * 640 + bn * 64 + tx * 4) = st;
        }
    }
}

// One wave per edge: score -> exp -> atomic scatter of p*m[src], p*r, and denom.
__global__ __launch_bounds__(256) void edge_scatter(
        const float* __restrict__ R, const int* __restrict__ src, const int* __restrict__ dst,
        const unsigned short* __restrict__ Y1,
        float* __restrict__ Xagg, float* __restrict__ denom, int E) {
    int e = blockIdx.x * 4 + (threadIdx.x >> 6);
    if (e >= E) return;
    int l = threadIdx.x & 63;
    int sIdx = src[e], dIdx = dst[e];
    const unsigned int* yd = (const unsigned int*)(Y1 + (size_t)dIdx * 640);
    const unsigned int* ys = (const unsigned int*)(Y1 + (size_t)sIdx * 640);
    unsigned int qu  = yd[l];         // q cols 2l,2l+1   (flat h*64+d)
    unsigned int t0u = yd[64 + l];    // t head0, f=2l,2l+1
    unsigned int t1u = yd[128 + l];   // t head1
    unsigned int ku  = ys[192 + l];   // k cols 2l,2l+1
    unsigned int mu  = ys[256 + l];   // m cols 2l,2l+1
    float2 rv = *(const float2*)(R + (size_t)e * 128 + 2 * l);
    float qx = bflo(qu),  qy = bfhi(qu);
    float kx = bflo(ku),  ky = bfhi(ku);
    float mx = bflo(mu),  my = bfhi(mu);
    float t0x = bflo(t0u), t0y = bfhi(t0u);
    float t1x = bflo(t1u), t1y = bfhi(t1u);
    float kqp = kx * qx + ky * qy;          // belongs to head (l>>5)
    float a0 = rv.x * t0x + rv.y * t0y;     // r . t[dst,h0]
    float a1 = rv.x * t1x + rv.y * t1y;     // r . t[dst,h1]
    if (l < 32) a0 += kqp; else a1 += kqp;
    #pragma unroll
    for (int o = 32; o; o >>= 1) {
        a0 += __shfl_xor(a0, o);
        a1 += __shfl_xor(a1, o);
    }
    a0 = (a0 >= 0.f) ? a0 : 0.01f * a0;     // LeakyReLU(0.01)
    a1 = (a1 >= 0.f) ? a1 : 0.01f * a1;
    // scores bounded (~|e|<=25), exp is fp32-safe without max subtraction
    float p0 = __expf(a0), p1 = __expf(a1);
    float* xd = Xagg + (size_t)dIdx * 384;
    float w = (l < 32) ? p0 : p1;
    atomicAdd(xd + 2 * l,           w * mx);    // magg
    atomicAdd(xd + 2 * l + 1,       w * my);
    atomicAdd(xd + 128 + 2 * l,     p0 * rv.x); // s head0
    atomicAdd(xd + 128 + 2 * l + 1, p0 * rv.y);
    atomicAdd(xd + 256 + 2 * l,     p1 * rv.x); // s head1
    atomicAdd(xd + 256 + 2 * l + 1, p1 * rv.y);
    if (l == 0) {
        atomicAdd(denom + (size_t)dIdx * 2,     p0);
        atomicAdd(denom + (size_t)dIdx * 2 + 1, p1);
    }
}

// out = [Xagg/denom | dial] (M x 640) @ W2 (640 x 64)
__global__ __launch_bounds__(256) void gemm_out(
        const float* __restrict__ Xagg, const float* __restrict__ denom,
        const float* __restrict__ dial, const float* __restrict__ W2,
        float* __restrict__ out, int M) {
    __shared__ float Xs[64 * 68];
    __shared__ float Ws[64 * 64];
    int m0 = blockIdx.x * 64;
    int tid = threadIdx.x;
    int tx = tid & 15, ty = tid >> 4;
    float acc[4][4] = {};
    for (int kc = 0; kc < 10; ++kc) {
        #pragma unroll
        for (int i = 0; i < 4; ++i) {
            int s = tid + i * 256;      // 1024 slots: 64 rows x 16 cv
            int row = s >> 4, cv = s & 15;
            int gr = m0 + row;
            int c0 = kc * 64 + cv * 4;
            float4 v = make_float4(0.f, 0.f, 0.f, 0.f);
            if (gr < M) {
                if (c0 < 384) {
                    v = *(const float4*)(Xagg + (size_t)gr * 384 + c0);
                    int h = (c0 < 128) ? (c0 >> 6) : ((c0 - 128) >> 7);
                    float den = denom[(size_t)gr * 2 + h];
                    float sc = (den > 0.f) ? (1.f / den) : 0.f;
                    v.x *= sc; v.y *= sc; v.z *= sc; v.w *= sc;
                } else {
                    v = *(const float4*)(dial + (size_t)gr * 256 + (c0 - 384));
                }
            }
            int k0 = cv * 4;
            Xs[(k0 + 0) * 68 + row] = v.x;
            Xs[(k0 + 1) * 68 + row] = v.y;
            Xs[(k0 + 2) * 68 + row] = v.z;
            Xs[(k0 + 3) * 68 + row] = v.w;
        }
        #pragma unroll
        for (int i = 0; i < 4; ++i) {
            int s = tid + i * 256;      // 1024 slots: 64 k x 16 cv
            int k = s >> 4, cv = s & 15;
            *(float4*)(Ws + k * 64 + cv * 4) =
                *(const float4*)(W2 + (size_t)(kc * 64 + k) * 64 + cv * 4);
        }
        __syncthreads();
        #pragma unroll 8
        for (int k = 0; k < 64; ++k) {
            float a[4];
            a[0] = Xs[k * 68 + ty * 4 + 0];
            a[1] = Xs[k * 68 + ty * 4 + 1];
            a[2] = Xs[k * 68 + ty * 4 + 2];
            a[3] = Xs[k * 68 + ty * 4 + 3];
            float4 b = *(const float4*)(Ws + k * 64 + tx * 4);
            #pragma unroll
            for (int i = 0; i < 4; ++i) {
                acc[i][0] += a[i] * b.x;
                acc[i][1] += a[i] * b.y;
                acc[i][2] += a[i] * b.z;
                acc[i][3] += a[i] * b.w;
            }
        }
        __syncthreads();
    }
    #pragma unroll
    for (int i = 0; i < 4; ++i) {
        int gr = m0 + ty * 4 + i;
        if (gr < M) {
            float4 st = make_float4(acc[i][0], acc[i][1], acc[i][2], acc[i][3]);
            *(float4*)(out + (size_t)gr * 64 + tx * 4) = st;
        }
    }
}

extern "C" void kernel_launch(void* const* d_in, const int* in_sizes, int n_in,
                              void* d_out, int out_size, void* d_ws, size_t ws_size,
                              hipStream_t stream) {
    const float* entity = (const float*)d_in[0];
    const float* rel    = (const float*)d_in[1];
    const float* dial   = (const float*)d_in[2];
    const float* wm     = (const float*)d_in[3];
    const float* wq     = (const float*)d_in[4];
    const float* wk     = (const float*)d_in[5];
    const float* whe    = (const float*)d_in[6];
    const float* whd    = (const float*)d_in[7];
    const int*   src    = (const int*)d_in[8];
    const int*   dst    = (const int*)d_in[9];
    int N = in_sizes[0] / 128;
    int E = in_sizes[8];
    float* out = (float*)d_out;

    // workspace layout (fp32 elements unless noted)
    float* ws    = (float*)d_ws;
    float* Xagg  = ws;                              // N*384
    float* denom = Xagg + (size_t)N * 384;          // N*2
    float* W1    = denom + (size_t)N * 2;           // 128*640
    float* W2    = W1 + 128 * 640;                  // 640*64
    unsigned short* Y1 = (unsigned short*)(W2 + 640 * 64); // N*640 bf16 (~128 MB)

    long n4 = ((long)N * 386) / 4;                  // Xagg+denom contiguous zero
    zero_f4<<<2048, 256, 0, stream>>>((float4*)ws, n4);
    build_w1<<<(128 * 640 + 255) / 256, 256, 0, stream>>>(wm, wq, wk, W1);
    build_w2<<<(640 * 64 + 255) / 256, 256, 0, stream>>>(wm, whe, whd, W2);
    dim3 g1((N + 63) / 64, 10);
    gemm_proj<<<g1, 256, 0, stream>>>(entity, W1, Y1, N);
    edge_scatter<<<(E + 3) / 4, 256, 0, stream>>>(rel, src, dst, Y1, Xagg, denom, E);
    gemm_out<<<(N + 63) / 64, 256, 0, stream>>>(Xagg, denom, dial, W2, out, N);
}

// Round 2
// 2010.183 us; speedup vs baseline: 2.6960x; 2.6960x over previous
//
#include <hip/hip_runtime.h>
#include <hip/hip_bf16.h>
#include <cstdint>

// Layouts:
//   Y1 (bf16, N x 640):  [ q(128: h*64+d) | t(256: h*128+f) | k(128) | m(128) ]
//   Xagg (f32, N x 384): [ magg(128) | s_h0(128) | s_h1(128) ]  (unnormalized)
//   W1 (f32, 128 x 640): projection weights (q | A(t) | k | m)
//   W2 (f32, 640 x 64):  [ w_h_entity(128) | P_h = w_m@w_h_e (256) | w_h_dialogue(256) ]
// Edge grouping: counting sort by dst -> off[N+1], elist[E]. One wave per node
// accumulates in registers; zero global atomics on the hot path.

__device__ __forceinline__ unsigned short f2bf(float x) {
    unsigned int u = __float_as_uint(x);
    u += 0x7FFFu + ((u >> 16) & 1u);   // round-to-nearest-even
    return (unsigned short)(u >> 16);
}
__device__ __forceinline__ float bflo(unsigned int u) { return __uint_as_float(u << 16); }
__device__ __forceinline__ float bfhi(unsigned int u) { return __uint_as_float(u & 0xFFFF0000u); }

__global__ void zero_f4(float4* __restrict__ p, long n4) {
    long i = (long)blockIdx.x * blockDim.x + threadIdx.x;
    long stride = (long)gridDim.x * blockDim.x;
    float4 z = make_float4(0.f, 0.f, 0.f, 0.f);
    for (; i < n4; i += stride) p[i] = z;
}

__global__ void build_w1(const float* __restrict__ wm, const float* __restrict__ wq,
                         const float* __restrict__ wk, float* __restrict__ W1) {
    int idx = blockIdx.x * blockDim.x + threadIdx.x;
    if (idx >= 128 * 640) return;
    int f = idx / 640, c = idx % 640;
    float v;
    if (c < 128) {                       // q
        int h = c >> 6, dd = c & 63;
        v = wq[h * 8192 + f * 64 + dd];
    } else if (c < 384) {                // t:  A[h,f,f2] = sum_d wq[h,f,d]*wm[h,f2,d]
        int cc = c - 128, h = cc >> 7, f2 = cc & 127;
        float s = 0.f;
        for (int dd = 0; dd < 64; ++dd)
            s += wq[h * 8192 + f * 64 + dd] * wm[h * 8192 + f2 * 64 + dd];
        v = s;
    } else if (c < 512) {                // k
        int cc = c - 384, h = cc >> 6, dd = cc & 63;
        v = wk[h * 8192 + f * 64 + dd];
    } else {                             // m
        int cc = c - 512, h = cc >> 6, dd = cc & 63;
        v = wm[h * 8192 + f * 64 + dd];
    }
    W1[idx] = v;
}

__global__ void build_w2(const float* __restrict__ wm, const float* __restrict__ whe,
                         const float* __restrict__ whd, float* __restrict__ W2) {
    int idx = blockIdx.x * blockDim.x + threadIdx.x;
    if (idx >= 640 * 64) return;
    int rr = idx / 64, j = idx % 64;
    float v;
    if (rr < 128) {                      // magg path: w_h_entity rows (h*64+d)
        v = whe[rr * 64 + j];
    } else if (rr < 384) {               // s path: P_h[f2,j] = sum_d wm[h,f2,d]*whe[h*64+d, j]
        int cc = rr - 128, h = cc >> 7, f2 = cc & 127;
        float s = 0.f;
        for (int dd = 0; dd < 64; ++dd)
            s += wm[h * 8192 + f2 * 64 + dd] * whe[(h * 64 + dd) * 64 + j];
        v = s;
    } else {                             // dialogue path
        v = whd[(rr - 384) * 64 + j];
    }
    W2[idx] = v;
}

// Y1 = entity_features (M x 128) @ W1 (128 x 640), stored bf16.
__global__ __launch_bounds__(256) void gemm_proj(
        const float* __restrict__ F, const float* __restrict__ W1,
        unsigned short* __restrict__ Y1, int M) {
    __shared__ float As[128 * 68];   // transposed [k][m], pad 64->68
    __shared__ float Bs[128 * 64];   // [k][n]
    int m0 = blockIdx.x * 64;
    int bn = blockIdx.y;
    int tid = threadIdx.x;
    #pragma unroll
    for (int i = 0; i < 8; ++i) {
        int s = tid + i * 256;          // 2048 float4 slots: 64 rows x 32 cv
        int row = s >> 5, cv = s & 31;
        int gr = m0 + row;
        float4 v = make_float4(0.f, 0.f, 0.f, 0.f);
        if (gr < M) v = *(const float4*)(F + (size_t)gr * 128 + cv * 4);
        int k0 = cv * 4;
        As[(k0 + 0) * 68 + row] = v.x;
        As[(k0 + 1) * 68 + row] = v.y;
        As[(k0 + 2) * 68 + row] = v.z;
        As[(k0 + 3) * 68 + row] = v.w;
    }
    #pragma unroll
    for (int i = 0; i < 8; ++i) {
        int s = tid + i * 256;          // 2048 float4 slots: 128 k x 16 cv
        int k = s >> 4, cv = s & 15;
        float4 v = *(const float4*)(W1 + (size_t)k * 640 + bn * 64 + cv * 4);
        *(float4*)(Bs + k * 64 + cv * 4) = v;
    }
    __syncthreads();
    int tx = tid & 15, ty = tid >> 4;
    float acc[4][4] = {};
    #pragma unroll 8
    for (int k = 0; k < 128; ++k) {
        float a[4];
        a[0] = As[k * 68 + ty * 4 + 0];
        a[1] = As[k * 68 + ty * 4 + 1];
        a[2] = As[k * 68 + ty * 4 + 2];
        a[3] = As[k * 68 + ty * 4 + 3];
        float4 b = *(const float4*)(Bs + k * 64 + tx * 4);
        #pragma unroll
        for (int i = 0; i < 4; ++i) {
            acc[i][0] += a[i] * b.x;
            acc[i][1] += a[i] * b.y;
            acc[i][2] += a[i] * b.z;
            acc[i][3] += a[i] * b.w;
        }
    }
    #pragma unroll
    for (int i = 0; i < 4; ++i) {
        int gr = m0 + ty * 4 + i;
        if (gr < M) {
            ushort4 st;
            st.x = f2bf(acc[i][0]);
            st.y = f2bf(acc[i][1]);
            st.z = f2bf(acc[i][2]);
            st.w = f2bf(acc[i][3]);
            *(ushort4*)(Y1 + (size_t)gr * 640 + bn * 64 + tx * 4) = st;
        }
    }
}

// ---- counting sort of edges by dst ----
__global__ void hist_dst(const int* __restrict__ dst, int* __restrict__ cnt, int E) {
    int e = blockIdx.x * blockDim.x + threadIdx.x;
    if (e < E) atomicAdd(&cnt[dst[e]], 1);
}

__global__ void scan_pass1(const int* __restrict__ cnt, int* __restrict__ bsum, int N) {
    __shared__ int sd[256];
    int i = blockIdx.x * 256 + threadIdx.x;
    sd[threadIdx.x] = (i < N) ? cnt[i] : 0;
    __syncthreads();
    for (int s = 128; s > 0; s >>= 1) {
        if (threadIdx.x < s) sd[threadIdx.x] += sd[threadIdx.x + s];
        __syncthreads();
    }
    if (threadIdx.x == 0) bsum[blockIdx.x] = sd[0];
}

__global__ void scan_pass2(int* __restrict__ bsum, int nb) {
    __shared__ int sd[1024];
    int t = threadIdx.x;
    int v = (t < nb) ? bsum[t] : 0;
    sd[t] = v;
    __syncthreads();
    for (int o = 1; o < 1024; o <<= 1) {
        int x = (t >= o) ? sd[t - o] : 0;
        __syncthreads();
        sd[t] += x;
        __syncthreads();
    }
    if (t < nb) bsum[t] = sd[t] - v;   // exclusive
}

__global__ void scan_pass3(const int* __restrict__ cnt, const int* __restrict__ bsum,
                           int* __restrict__ off, int* __restrict__ cursor, int N, int E) {
    __shared__ int sd[256];
    int t = threadIdx.x;
    int i = blockIdx.x * 256 + t;
    int v = (i < N) ? cnt[i] : 0;
    sd[t] = v;
    __syncthreads();
    for (int o = 1; o < 256; o <<= 1) {
        int x = (t >= o) ? sd[t - o] : 0;
        __syncthreads();
        sd[t] += x;
        __syncthreads();
    }
    int excl = sd[t] - v + bsum[blockIdx.x];
    if (i < N) { off[i] = excl; cursor[i] = excl; }
    if (i == N - 1) off[N] = E;
}

__global__ void scatter_edges(const int* __restrict__ dst, int* __restrict__ cursor,
                              int* __restrict__ elist, int E) {
    int e = blockIdx.x * blockDim.x + threadIdx.x;
    if (e < E) {
        int p = atomicAdd(&cursor[dst[e]], 1);
        elist[p] = e;
    }
}

// One wave per node: loop incoming edges, accumulate in registers, store once.
__global__ __launch_bounds__(256) void node_gather(
        const float* __restrict__ R, const int* __restrict__ srcArr,
        const int* __restrict__ off, const int* __restrict__ elist,
        const unsigned short* __restrict__ Y1,
        float* __restrict__ Xagg, float* __restrict__ denom, int N) {
    int n = blockIdx.x * 4 + (threadIdx.x >> 6);
    if (n >= N) return;
    int l = threadIdx.x & 63;
    const unsigned int* yd = (const unsigned int*)(Y1 + (size_t)n * 640);
    unsigned int qu = yd[l], t0u = yd[64 + l], t1u = yd[128 + l];
    float qx = bflo(qu),  qy = bfhi(qu);
    float t0x = bflo(t0u), t0y = bfhi(t0u);
    float t1x = bflo(t1u), t1y = bfhi(t1u);
    int e0 = off[n], e1 = off[n + 1];
    float maccx = 0.f, maccy = 0.f;
    float s0x = 0.f, s0y = 0.f, s1x = 0.f, s1y = 0.f;
    float den0 = 0.f, den1 = 0.f;
    for (int e = e0; e < e1; ++e) {
        int eid = elist[e];
        int sI = srcArr[eid];
        const unsigned int* ys = (const unsigned int*)(Y1 + (size_t)sI * 640);
        unsigned int ku = ys[192 + l];
        unsigned int mu = ys[256 + l];
        float2 rv = *(const float2*)(R + (size_t)eid * 128 + 2 * l);
        float kx = bflo(ku), ky = bfhi(ku);
        float mx = bflo(mu), my = bfhi(mu);
        float kqp = kx * qx + ky * qy;           // head = l>>5
        float a0 = rv.x * t0x + rv.y * t0y;      // r . t[dst,h0]
        float a1 = rv.x * t1x + rv.y * t1y;      // r . t[dst,h1]
        if (l < 32) a0 += kqp; else a1 += kqp;
        #pragma unroll
        for (int o = 32; o; o >>= 1) {
            a0 += __shfl_xor(a0, o);
            a1 += __shfl_xor(a1, o);
        }
        a0 = (a0 >= 0.f) ? a0 : 0.01f * a0;      // LeakyReLU(0.01)
        a1 = (a1 >= 0.f) ? a1 : 0.01f * a1;
        float p0 = __expf(a0), p1 = __expf(a1);  // scores bounded, fp32-safe
        float w = (l < 32) ? p0 : p1;
        maccx += w * mx;  maccy += w * my;
        s0x += p0 * rv.x; s0y += p0 * rv.y;
        s1x += p1 * rv.x; s1y += p1 * rv.y;
        den0 += p0; den1 += p1;
    }
    float* xd = Xagg + (size_t)n * 384;
    *(float2*)(xd + 2 * l)       = make_float2(maccx, maccy);
    *(float2*)(xd + 128 + 2 * l) = make_float2(s0x, s0y);
    *(float2*)(xd + 256 + 2 * l) = make_float2(s1x, s1y);
    if (l == 0) {
        denom[(size_t)n * 2]     = den0;
        denom[(size_t)n * 2 + 1] = den1;
    }
}

// out = [Xagg/denom | dial] (M x 640) @ W2 (640 x 64)
__global__ __launch_bounds__(256) void gemm_out(
        const float* __restrict__ Xagg, const float* __restrict__ denom,
        const float* __restrict__ dial, const float* __restrict__ W2,
        float* __restrict__ out, int M) {
    __shared__ float Xs[64 * 68];
    __shared__ float Ws[64 * 64];
    int m0 = blockIdx.x * 64;
    int tid = threadIdx.x;
    int tx = tid & 15, ty = tid >> 4;
    float acc[4][4] = {};
    for (int kc = 0; kc < 10; ++kc) {
        #pragma unroll
        for (int i = 0; i < 4; ++i) {
            int s = tid + i * 256;      // 1024 slots: 64 rows x 16 cv
            int row = s >> 4, cv = s & 15;
            int gr = m0 + row;
            int c0 = kc * 64 + cv * 4;
            float4 v = make_float4(0.f, 0.f, 0.f, 0.f);
            if (gr < M) {
                if (c0 < 384) {
                    v = *(const float4*)(Xagg + (size_t)gr * 384 + c0);
                    int h = (c0 < 128) ? (c0 >> 6) : ((c0 - 128) >> 7);
                    float den = denom[(size_t)gr * 2 + h];
                    float sc = (den > 0.f) ? (1.f / den) : 0.f;
                    v.x *= sc; v.y *= sc; v.z *= sc; v.w *= sc;
                } else {
                    v = *(const float4*)(dial + (size_t)gr * 256 + (c0 - 384));
                }
            }
            int k0 = cv * 4;
            Xs[(k0 + 0) * 68 + row] = v.x;
            Xs[(k0 + 1) * 68 + row] = v.y;
            Xs[(k0 + 2) * 68 + row] = v.z;
            Xs[(k0 + 3) * 68 + row] = v.w;
        }
        #pragma unroll
        for (int i = 0; i < 4; ++i) {
            int s = tid + i * 256;      // 1024 slots: 64 k x 16 cv
            int k = s >> 4, cv = s & 15;
            *(float4*)(Ws + k * 64 + cv * 4) =
                *(const float4*)(W2 + (size_t)(kc * 64 + k) * 64 + cv * 4);
        }
        __syncthreads();
        #pragma unroll 8
        for (int k = 0; k < 64; ++k) {
            float a[4];
            a[0] = Xs[k * 68 + ty * 4 + 0];
            a[1] = Xs[k * 68 + ty * 4 + 1];
            a[2] = Xs[k * 68 + ty * 4 + 2];
            a[3] = Xs[k * 68 + ty * 4 + 3];
            float4 b = *(const float4*)(Ws + k * 64 + tx * 4);
            #pragma unroll
            for (int i = 0; i < 4; ++i) {
                acc[i][0] += a[i] * b.x;
                acc[i][1] += a[i] * b.y;
                acc[i][2] += a[i] * b.z;
                acc[i][3] += a[i] * b.w;
            }
        }
        __syncthreads();
    }
    #pragma unroll
    for (int i = 0; i < 4; ++i) {
        int gr = m0 + ty * 4 + i;
        if (gr < M) {
            float4 st = make_float4(acc[i][0], acc[i][1], acc[i][2], acc[i][3]);
            *(float4*)(out + (size_t)gr * 64 + tx * 4) = st;
        }
    }
}

extern "C" void kernel_launch(void* const* d_in, const int* in_sizes, int n_in,
                              void* d_out, int out_size, void* d_ws, size_t ws_size,
                              hipStream_t stream) {
    const float* entity = (const float*)d_in[0];
    const float* rel    = (const float*)d_in[1];
    const float* dial   = (const float*)d_in[2];
    const float* wm     = (const float*)d_in[3];
    const float* wq     = (const float*)d_in[4];
    const float* wk     = (const float*)d_in[5];
    const float* whe    = (const float*)d_in[6];
    const float* whd    = (const float*)d_in[7];
    const int*   src    = (const int*)d_in[8];
    const int*   dst    = (const int*)d_in[9];
    int N = in_sizes[0] / 128;
    int E = in_sizes[8];
    float* out = (float*)d_out;

    // workspace layout
    float* ws    = (float*)d_ws;
    float* Xagg  = ws;                              // N*384 f32
    float* denom = Xagg + (size_t)N * 384;          // N*2
    float* W1    = denom + (size_t)N * 2;           // 128*640
    float* W2    = W1 + 128 * 640;                  // 640*64
    unsigned short* Y1 = (unsigned short*)(W2 + 640 * 64); // N*640 bf16
    int* ip      = (int*)(Y1 + (size_t)N * 640);
    int* cnt     = ip;                              // N
    int* offp    = cnt + N;                         // N+1
    int* cursor  = offp + N + 1;                    // N
    int* elist   = cursor + N;                      // E
    int* bsum    = elist + E;                       // up to 1024

    int nb = (N + 255) / 256;                       // scan blocks (<=1024)

    zero_f4<<<256, 256, 0, stream>>>((float4*)cnt, (long)N / 4);
    build_w1<<<(128 * 640 + 255) / 256, 256, 0, stream>>>(wm, wq, wk, W1);
    build_w2<<<(640 * 64 + 255) / 256, 256, 0, stream>>>(wm, whe, whd, W2);
    dim3 g1((N + 63) / 64, 10);
    gemm_proj<<<g1, 256, 0, stream>>>(entity, W1, Y1, N);
    hist_dst<<<(E + 255) / 256, 256, 0, stream>>>(dst, cnt, E);
    scan_pass1<<<nb, 256, 0, stream>>>(cnt, bsum, N);
    scan_pass2<<<1, 1024, 0, stream>>>(bsum, nb);
    scan_pass3<<<nb, 256, 0, stream>>>(cnt, bsum, offp, cursor, N, E);
    scatter_edges<<<(E + 255) / 256, 256, 0, stream>>>(dst, cursor, elist, E);
    node_gather<<<(N + 3) / 4, 256, 0, stream>>>(rel, src, offp, elist, Y1, Xagg, denom, N);
    gemm_out<<<(N + 63) / 64, 256, 0, stream>>>(Xagg, denom, dial, W2, out, N);
}